// Round 2
// baseline (1141.879 us; speedup 1.0000x reference)
//
#include <hip/hip_runtime.h>
#include <hip/hip_bf16.h>

typedef __bf16 bf16;
typedef __bf16 bf16x8 __attribute__((ext_vector_type(8)));
typedef float f32x4 __attribute__((ext_vector_type(4)));

// B=16, H=W=56, C=512, HEADS=16, hd=32, WS=7, SHIFT=3, N=49, NW=64
#define M_TOK 50176

__device__ __forceinline__ int regid(int u) { return u < 49 ? 0 : (u < 53 ? 1 : 2); }

// ---------------- weight fp32 -> bf16 conversion (4 segments, packed dst)
__global__ __launch_bounds__(256) void convert_w_kernel(
    const float* __restrict__ w0, const float* __restrict__ w1,
    const float* __restrict__ w2, const float* __restrict__ w3,
    bf16* __restrict__ dst)
{
    int blk = blockIdx.x;
    const float* src; size_t srel, drel;
    if (blk < 768)       { src = w0; srel = (size_t)blk * 1024;          drel = srel; }
    else if (blk < 1024) { src = w1; srel = (size_t)(blk - 768) * 1024;  drel = 786432 + srel; }
    else if (blk < 2048) { src = w2; srel = (size_t)(blk - 1024) * 1024; drel = 1048576 + srel; }
    else                 { src = w3; srel = (size_t)(blk - 2048) * 1024; drel = 2097152 + srel; }
    int i = threadIdx.x * 4;
    float4 v = *(const float4*)(src + srel + i);
    bf16* d = dst + drel + i;
    d[0] = (bf16)v.x; d[1] = (bf16)v.y; d[2] = (bf16)v.z; d[3] = (bf16)v.w;
}

// ---------------- LN1 + cyclic shift + window partition -> h (window-token order, bf16)
__global__ __launch_bounds__(256) void ln1_window_kernel(
    const float* __restrict__ x, const float* __restrict__ g, const float* __restrict__ bta,
    bf16* __restrict__ h)
{
    int t = blockIdx.x;                 // window-token index
    int win = t / 49, n = t - win * 49;
    int bi = win >> 6, nw = win & 63;
    int wh = nw >> 3, ww = nw & 7;
    int ny = n / 7, nx = n - ny * 7;
    int r = wh * 7 + ny + 3; if (r >= 56) r -= 56;   // roll(-3)
    int c = ww * 7 + nx + 3; if (c >= 56) c -= 56;
    const float* xr = x + ((size_t)bi * 3136 + r * 56 + c) * 512;
    int tid = threadIdx.x;
    float v0 = xr[tid];
    float v1 = xr[tid + 256];
    float s = v0 + v1, ss = v0 * v0 + v1 * v1;
#pragma unroll
    for (int o = 32; o; o >>= 1) { s += __shfl_down(s, o, 64); ss += __shfl_down(ss, o, 64); }
    __shared__ float red[8];
    int wave = tid >> 6, lane = tid & 63;
    if (lane == 0) { red[wave] = s; red[4 + wave] = ss; }
    __syncthreads();
    float S = red[0] + red[1] + red[2] + red[3];
    float SS = red[4] + red[5] + red[6] + red[7];
    float mean = S * (1.f / 512.f);
    float var = SS * (1.f / 512.f) - mean * mean;
    float rstd = rsqrtf(var + 1e-5f);
    bf16* hr = h + (size_t)t * 512;
    hr[tid] = (bf16)((v0 - mean) * rstd * g[tid] + bta[tid]);
    hr[tid + 256] = (bf16)((v1 - mean) * rstd * g[tid + 256] + bta[tid + 256]);
}

// ---------------- LN2 (natural token order), x1 fp32 -> bf16 out
__global__ __launch_bounds__(256) void ln2_kernel(
    const float* __restrict__ x1, const float* __restrict__ g,
    const float* __restrict__ bta, bf16* __restrict__ outp)
{
    int t = blockIdx.x;
    int tid = threadIdx.x;
    const float* xr = x1 + (size_t)t * 512;
    float v0 = xr[tid], v1 = xr[tid + 256];
    float s = v0 + v1, ss = v0 * v0 + v1 * v1;
#pragma unroll
    for (int o = 32; o; o >>= 1) { s += __shfl_down(s, o, 64); ss += __shfl_down(ss, o, 64); }
    __shared__ float red[8];
    int wave = tid >> 6, lane = tid & 63;
    if (lane == 0) { red[wave] = s; red[4 + wave] = ss; }
    __syncthreads();
    float S = red[0] + red[1] + red[2] + red[3];
    float SS = red[4] + red[5] + red[6] + red[7];
    float mean = S * (1.f / 512.f);
    float var = SS * (1.f / 512.f) - mean * mean;
    float rstd = rsqrtf(var + 1e-5f);
    bf16* hr = outp + (size_t)t * 512;
    hr[tid] = (bf16)((v0 - mean) * rstd * g[tid] + bta[tid]);
    hr[tid + 256] = (bf16)((v1 - mean) * rstd * g[tid + 256] + bta[tid + 256]);
}

// ---------------- generic MFMA GEMM: C[M,N] = A[M,K] @ W[N,K]^T + bias
// A, W bf16; bias fp32.
// MODE 0: bf16 store   MODE 1: GELU -> bf16 store
// MODE 2: window-reverse+unshift scatter, + fp32 x -> fp32 out
// MODE 3: + fp32 x1 residual -> fp32 out
template <int MODE>
__global__ __launch_bounds__(256) void gemm_kernel(
    const bf16* __restrict__ A, const bf16* __restrict__ Wt, const float* __restrict__ bias,
    void* __restrict__ outp, const float* __restrict__ extra, int N, int K)
{
    __shared__ bf16 As[64][40];
    __shared__ bf16 Ws[64][40];
    int bm = blockIdx.x, bn = blockIdx.y;
    int tid = threadIdx.x;
    int wave = tid >> 6, lane = tid & 63;
    int wm = wave >> 1, wn = wave & 1;       // 2x2 waves, each 32x32 output
    int r0 = tid >> 2, cg = tid & 3;         // staging: 64 rows x 4 chunks of 8 bf16
    const bf16* Ap = A + (size_t)(bm * 64 + r0) * K + cg * 8;
    const bf16* Wp = Wt + (size_t)(bn * 64 + r0) * K + cg * 8;
    f32x4 z = {0.f, 0.f, 0.f, 0.f};
    f32x4 acc[2][2] = {{z, z}, {z, z}};
    int fr = lane & 15, fq = lane >> 4;
    int ko = fq * 8;
    for (int k0 = 0; k0 < K; k0 += 32) {
        uint4 av = *(const uint4*)(Ap + k0);
        uint4 wv = *(const uint4*)(Wp + k0);
        __syncthreads();
        *(uint4*)&As[r0][cg * 8] = av;
        *(uint4*)&Ws[r0][cg * 8] = wv;
        __syncthreads();
        bf16x8 a0 = *(const bf16x8*)&As[wm * 32 + fr][ko];
        bf16x8 a1 = *(const bf16x8*)&As[wm * 32 + 16 + fr][ko];
        bf16x8 b0 = *(const bf16x8*)&Ws[wn * 32 + fr][ko];
        bf16x8 b1 = *(const bf16x8*)&Ws[wn * 32 + 16 + fr][ko];
        acc[0][0] = __builtin_amdgcn_mfma_f32_16x16x32_bf16(a0, b0, acc[0][0], 0, 0, 0);
        acc[0][1] = __builtin_amdgcn_mfma_f32_16x16x32_bf16(a0, b1, acc[0][1], 0, 0, 0);
        acc[1][0] = __builtin_amdgcn_mfma_f32_16x16x32_bf16(a1, b0, acc[1][0], 0, 0, 0);
        acc[1][1] = __builtin_amdgcn_mfma_f32_16x16x32_bf16(a1, b1, acc[1][1], 0, 0, 0);
    }
#pragma unroll
    for (int mi = 0; mi < 2; mi++)
#pragma unroll
        for (int ni = 0; ni < 2; ni++)
#pragma unroll
            for (int r = 0; r < 4; r++) {
                int row = bm * 64 + wm * 32 + mi * 16 + fq * 4 + r;
                int col = bn * 64 + wn * 32 + ni * 16 + fr;
                float v = acc[mi][ni][r] + bias[col];
                if constexpr (MODE == 0) {
                    ((bf16*)outp)[(size_t)row * N + col] = (bf16)v;
                } else if constexpr (MODE == 1) {
                    v = 0.5f * v * (1.f + erff(v * 0.70710678118654752f));
                    ((bf16*)outp)[(size_t)row * N + col] = (bf16)v;
                } else if constexpr (MODE == 2) {
                    int win = row / 49, n = row - win * 49;
                    int bi = win >> 6, nw = win & 63;
                    int wh = nw >> 3, wwi = nw & 7;
                    int ny = n / 7, nx = n - ny * 7;
                    int rr = wh * 7 + ny + 3; if (rr >= 56) rr -= 56;
                    int cc = wwi * 7 + nx + 3; if (cc >= 56) cc -= 56;
                    size_t dst = ((size_t)bi * 3136 + rr * 56 + cc) * 512 + col;
                    ((float*)outp)[dst] = v + extra[dst];
                } else {
                    size_t dst = (size_t)row * 512 + col;
                    ((float*)outp)[dst] = v + extra[dst];
                }
            }
}

// ---------------- attention: one wave per (window, head). N=49, hd=32.
__global__ __launch_bounds__(64) void attn_kernel(
    const bf16* __restrict__ qkv, const float* __restrict__ rpb, bf16* __restrict__ outp)
{
    int wid = blockIdx.x;
    int win = wid >> 4, head = wid & 15;
    int nw = win & 63;
    int wh = nw >> 3, ww = nw & 7;
    int lane = threadIdx.x;
    __shared__ bf16 Ks[49 * 32];
    __shared__ bf16 Vs[49 * 32];
    const bf16* base = qkv + (size_t)win * 49 * 1536 + head * 32;
    for (int c = lane; c < 196; c += 64) {
        int i = c >> 2, p4 = c & 3;
        *(uint4*)&Ks[i * 32 + p4 * 8] = *(const uint4*)(base + (size_t)i * 1536 + 512 + p4 * 8);
        *(uint4*)&Vs[i * 32 + p4 * 8] = *(const uint4*)(base + (size_t)i * 1536 + 1024 + p4 * 8);
    }
    __syncthreads();
    if (lane >= 49) return;
    float q[32];
    const bf16* qr = base + (size_t)lane * 1536;
#pragma unroll
    for (int d = 0; d < 32; d++) q[d] = (float)qr[d] * 0.17677669529663689f;
    int yi = lane / 7, xi = lane - yi * 7;
    int idi = 3 * regid(wh * 7 + yi) + regid(ww * 7 + xi);
    float p[49];
    float mx = -1e30f;
#pragma unroll
    for (int j = 0; j < 49; j++) {
        float s = 0.f;
#pragma unroll
        for (int d = 0; d < 32; d++) s += q[d] * (float)Ks[j * 32 + d];
        int yj = j / 7, xj = j - yj * 7;
        int idj = 3 * regid(wh * 7 + yj) + regid(ww * 7 + xj);
        int ridx = (yi - yj + 6) * 13 + (xi - xj + 6);
        s += rpb[ridx * 16 + head];
        if (idj != idi) s -= 100.f;
        p[j] = s;
        mx = fmaxf(mx, s);
    }
    float sum = 0.f;
#pragma unroll
    for (int j = 0; j < 49; j++) { p[j] = __expf(p[j] - mx); sum += p[j]; }
    float inv = 1.f / sum;
    float o[32];
#pragma unroll
    for (int d = 0; d < 32; d++) o[d] = 0.f;
#pragma unroll
    for (int j = 0; j < 49; j++) {
        float pv = p[j] * inv;
#pragma unroll
        for (int d = 0; d < 32; d++) o[d] += pv * (float)Vs[j * 32 + d];
    }
    bf16* orow = outp + (size_t)(win * 49 + lane) * 512 + head * 32;
#pragma unroll
    for (int d = 0; d < 32; d++) orow[d] = (bf16)o[d];
}

extern "C" void kernel_launch(void* const* d_in, const int* in_sizes, int n_in,
                              void* d_out, int out_size, void* d_ws, size_t ws_size,
                              hipStream_t stream)
{
    const float* x      = (const float*)d_in[0];
    const float* n1g    = (const float*)d_in[1];
    const float* n1b    = (const float*)d_in[2];
    const float* qkv_w  = (const float*)d_in[3];
    const float* qkv_b  = (const float*)d_in[4];
    const float* proj_w = (const float*)d_in[5];
    const float* proj_b = (const float*)d_in[6];
    const float* rpb    = (const float*)d_in[7];
    const float* n2g    = (const float*)d_in[8];
    const float* n2b    = (const float*)d_in[9];
    const float* fc1_w  = (const float*)d_in[10];
    const float* fc1_b  = (const float*)d_in[11];
    const float* fc2_w  = (const float*)d_in[12];
    const float* fc2_b  = (const float*)d_in[13];

    char* ws = (char*)d_ws;
    // layout (bytes):
    //   [0, 154140672)            qkv bf16 (50176 x 1536)        } hid (50176 x 2048 bf16)
    //   [154140672, 205520896)    h   bf16 (50176 x 512)         }   overlays exactly
    //   [205520896, 256901120)    attn_out bf16 -> later ln2h bf16
    //   [256901120, 263192576)    weights bf16 (qkv_w | proj_w | fc1_w | fc2_w)
    // x1 (fp32, 50176x512) lives in d_out (exact size match).
    bf16* qkv  = (bf16*)ws;
    bf16* h    = (bf16*)(ws + 154140672ull);
    bf16* ao   = (bf16*)(ws + 205520896ull);
    bf16* wbuf = (bf16*)(ws + 256901120ull);
    bf16* hid  = (bf16*)ws;          // overlays qkv+h (dead by then)
    bf16* ln2h = ao;                 // overlays attn_out (dead by then)
    bf16* wq  = wbuf;
    bf16* wp  = wbuf + 786432;
    bf16* wf1 = wbuf + 1048576;
    bf16* wf2 = wbuf + 2097152;
    float* x1 = (float*)d_out;

    convert_w_kernel<<<3072, 256, 0, stream>>>(qkv_w, proj_w, fc1_w, fc2_w, wbuf);
    ln1_window_kernel<<<M_TOK, 256, 0, stream>>>(x, n1g, n1b, h);
    gemm_kernel<0><<<dim3(784, 24), 256, 0, stream>>>(h, wq, qkv_b, qkv, nullptr, 1536, 512);
    attn_kernel<<<16384, 64, 0, stream>>>(qkv, rpb, ao);
    gemm_kernel<2><<<dim3(784, 8), 256, 0, stream>>>(ao, wp, proj_b, x1, x, 512, 512);
    ln2_kernel<<<M_TOK, 256, 0, stream>>>(x1, n2g, n2b, ln2h);
    gemm_kernel<1><<<dim3(784, 32), 256, 0, stream>>>(ln2h, wf1, fc1_b, hid, nullptr, 2048, 512);
    gemm_kernel<3><<<dim3(784, 8), 256, 0, stream>>>(hid, wf2, fc2_b, d_out, x1, 512, 2048);
}

// Round 3
// 988.768 us; speedup vs baseline: 1.1549x; 1.1549x over previous
//
#include <hip/hip_runtime.h>
#include <hip/hip_bf16.h>

typedef __bf16 bf16;
typedef __bf16 bf16x8 __attribute__((ext_vector_type(8)));
typedef float f32x4 __attribute__((ext_vector_type(4)));

// B=16, H=W=56, C=512, HEADS=16, hd=32, WS=7, SHIFT=3, N=49, NW=64
#define M_TOK 50176

__device__ __forceinline__ int regid(int u) { return u < 49 ? 0 : (u < 53 ? 1 : 2); }

#define GLD16(dst, src) __builtin_amdgcn_global_load_lds( \
    (const __attribute__((address_space(1))) void*)(src), \
    (__attribute__((address_space(3))) void*)(dst), 16, 0, 0)

// ---------------- weight fp32 -> bf16 conversion (4 segments, packed dst)
__global__ __launch_bounds__(256) void convert_w_kernel(
    const float* __restrict__ w0, const float* __restrict__ w1,
    const float* __restrict__ w2, const float* __restrict__ w3,
    bf16* __restrict__ dst)
{
    int blk = blockIdx.x;
    const float* src; size_t srel, drel;
    if (blk < 768)       { src = w0; srel = (size_t)blk * 1024;          drel = srel; }
    else if (blk < 1024) { src = w1; srel = (size_t)(blk - 768) * 1024;  drel = 786432 + srel; }
    else if (blk < 2048) { src = w2; srel = (size_t)(blk - 1024) * 1024; drel = 1048576 + srel; }
    else                 { src = w3; srel = (size_t)(blk - 2048) * 1024; drel = 2097152 + srel; }
    int i = threadIdx.x * 4;
    float4 v = *(const float4*)(src + srel + i);
    bf16* d = dst + drel + i;
    d[0] = (bf16)v.x; d[1] = (bf16)v.y; d[2] = (bf16)v.z; d[3] = (bf16)v.w;
}

// ---------------- LN1 + cyclic shift + window partition -> h (window-token order, bf16)
__global__ __launch_bounds__(256) void ln1_window_kernel(
    const float* __restrict__ x, const float* __restrict__ g, const float* __restrict__ bta,
    bf16* __restrict__ h)
{
    int t = blockIdx.x;                 // window-token index
    int win = t / 49, n = t - win * 49;
    int bi = win >> 6, nw = win & 63;
    int wh = nw >> 3, ww = nw & 7;
    int ny = n / 7, nx = n - ny * 7;
    int r = wh * 7 + ny + 3; if (r >= 56) r -= 56;   // roll(-3)
    int c = ww * 7 + nx + 3; if (c >= 56) c -= 56;
    const float* xr = x + ((size_t)bi * 3136 + r * 56 + c) * 512;
    int tid = threadIdx.x;
    float v0 = xr[tid];
    float v1 = xr[tid + 256];
    float s = v0 + v1, ss = v0 * v0 + v1 * v1;
#pragma unroll
    for (int o = 32; o; o >>= 1) { s += __shfl_down(s, o, 64); ss += __shfl_down(ss, o, 64); }
    __shared__ float red[8];
    int wave = tid >> 6, lane = tid & 63;
    if (lane == 0) { red[wave] = s; red[4 + wave] = ss; }
    __syncthreads();
    float S = red[0] + red[1] + red[2] + red[3];
    float SS = red[4] + red[5] + red[6] + red[7];
    float mean = S * (1.f / 512.f);
    float var = SS * (1.f / 512.f) - mean * mean;
    float rstd = rsqrtf(var + 1e-5f);
    bf16* hr = h + (size_t)t * 512;
    hr[tid] = (bf16)((v0 - mean) * rstd * g[tid] + bta[tid]);
    hr[tid + 256] = (bf16)((v1 - mean) * rstd * g[tid + 256] + bta[tid + 256]);
}

// ---------------- LN2 (natural token order), x1 fp32 -> bf16 out
__global__ __launch_bounds__(256) void ln2_kernel(
    const float* __restrict__ x1, const float* __restrict__ g,
    const float* __restrict__ bta, bf16* __restrict__ outp)
{
    int t = blockIdx.x;
    int tid = threadIdx.x;
    const float* xr = x1 + (size_t)t * 512;
    float v0 = xr[tid], v1 = xr[tid + 256];
    float s = v0 + v1, ss = v0 * v0 + v1 * v1;
#pragma unroll
    for (int o = 32; o; o >>= 1) { s += __shfl_down(s, o, 64); ss += __shfl_down(ss, o, 64); }
    __shared__ float red[8];
    int wave = tid >> 6, lane = tid & 63;
    if (lane == 0) { red[wave] = s; red[4 + wave] = ss; }
    __syncthreads();
    float S = red[0] + red[1] + red[2] + red[3];
    float SS = red[4] + red[5] + red[6] + red[7];
    float mean = S * (1.f / 512.f);
    float var = SS * (1.f / 512.f) - mean * mean;
    float rstd = rsqrtf(var + 1e-5f);
    bf16* hr = outp + (size_t)t * 512;
    hr[tid] = (bf16)((v0 - mean) * rstd * g[tid] + bta[tid]);
    hr[tid + 256] = (bf16)((v1 - mean) * rstd * g[tid + 256] + bta[tid + 256]);
}

// ---------------- 128x128 MFMA GEMM (m97 structure): C[M,N] = A[M,K] @ W[N,K]^T + bias
// 4 waves (2x2), each computing 64x64 via 4x4 16x16x32 fragments. BK=32.
// global_load_lds width-16 staging into linear LDS tiles.
// MODE 0: bf16 store   MODE 1: GELU -> bf16 store
// MODE 2: window-reverse+unshift scatter, + fp32 x -> fp32 out
// MODE 3: + fp32 x1 residual -> fp32 out
template <int MODE, int K>
__global__ __launch_bounds__(256) void gemm128_kernel(
    const bf16* __restrict__ A, const bf16* __restrict__ Wt, const float* __restrict__ bias,
    void* __restrict__ outp, const float* __restrict__ extra, int N)
{
    __shared__ bf16 As[128][32];
    __shared__ bf16 Ws[128][32];
    int bn = blockIdx.x, bm = blockIdx.y;     // x = N-tiles so consecutive blocks share A-panel
    int tid = threadIdx.x;
    int wave = tid >> 6, lane = tid & 63;
    int wm = wave >> 1, wn = wave & 1;        // 2x2 waves, each 64x64 output
    int fr = lane & 15, fq = lane >> 4;
    int ko = fq * 8;
    // staging geometry: each wave stages 2 chunks of 1KB for A and 2 for B.
    // chunk c covers rows [c*16, c*16+16) of the 128x32 tile; lane l -> row c*16 + (l>>2),
    // k-elems (l&3)*8.
    int rs = lane >> 2, cs = (lane & 3) * 8;
    const bf16* gA0 = A + (size_t)(bm * 128 + wave * 32 + rs) * K + cs;
    const bf16* gA1 = gA0 + (size_t)16 * K;
    const bf16* gB0 = Wt + (size_t)(bn * 128 + wave * 32 + rs) * K + cs;
    const bf16* gB1 = gB0 + (size_t)16 * K;
    bf16* lA0 = &As[wave * 32][0];
    bf16* lA1 = &As[wave * 32 + 16][0];
    bf16* lB0 = &Ws[wave * 32][0];
    bf16* lB1 = &Ws[wave * 32 + 16][0];
    f32x4 z = {0.f, 0.f, 0.f, 0.f};
    f32x4 acc[4][4];
#pragma unroll
    for (int mi = 0; mi < 4; mi++)
#pragma unroll
        for (int ni = 0; ni < 4; ni++) acc[mi][ni] = z;

    for (int k0 = 0; k0 < K; k0 += 32) {
        GLD16(lA0, gA0 + k0);
        GLD16(lA1, gA1 + k0);
        GLD16(lB0, gB0 + k0);
        GLD16(lB1, gB1 + k0);
        asm volatile("s_waitcnt vmcnt(0)" ::: "memory");
        __syncthreads();
        bf16x8 a[4], b[4];
#pragma unroll
        for (int i = 0; i < 4; i++) {
            a[i] = *(const bf16x8*)&As[wm * 64 + i * 16 + fr][ko];
            b[i] = *(const bf16x8*)&Ws[wn * 64 + i * 16 + fr][ko];
        }
#pragma unroll
        for (int mi = 0; mi < 4; mi++)
#pragma unroll
            for (int ni = 0; ni < 4; ni++)
                acc[mi][ni] = __builtin_amdgcn_mfma_f32_16x16x32_bf16(a[mi], b[ni], acc[mi][ni], 0, 0, 0);
        __syncthreads();
    }

#pragma unroll
    for (int mi = 0; mi < 4; mi++) {
#pragma unroll
        for (int r = 0; r < 4; r++) {
            int row = bm * 128 + wm * 64 + mi * 16 + fq * 4 + r;
            size_t rowbase;
            if constexpr (MODE == 2) {
                int win = row / 49, n = row - win * 49;
                int bi = win >> 6, nw = win & 63;
                int wh = nw >> 3, wwi = nw & 7;
                int ny = n / 7, nx = n - ny * 7;
                int rr = wh * 7 + ny + 3; if (rr >= 56) rr -= 56;
                int cc = wwi * 7 + nx + 3; if (cc >= 56) cc -= 56;
                rowbase = ((size_t)bi * 3136 + rr * 56 + cc) * 512;
            } else {
                rowbase = (size_t)row * (MODE == 3 ? 512 : N);
            }
#pragma unroll
            for (int ni = 0; ni < 4; ni++) {
                int col = bn * 128 + wn * 64 + ni * 16 + fr;
                float v = acc[mi][ni][r] + bias[col];
                if constexpr (MODE == 0) {
                    ((bf16*)outp)[rowbase + col] = (bf16)v;
                } else if constexpr (MODE == 1) {
                    v = 0.5f * v * (1.f + erff(v * 0.70710678118654752f));
                    ((bf16*)outp)[rowbase + col] = (bf16)v;
                } else {
                    size_t dst = rowbase + col;
                    ((float*)outp)[dst] = v + extra[dst];
                }
            }
        }
    }
}

// ---------------- attention: one wave per (window, head). N=49, hd=32.
__global__ __launch_bounds__(64) void attn_kernel(
    const bf16* __restrict__ qkv, const float* __restrict__ rpb, bf16* __restrict__ outp)
{
    int wid = blockIdx.x;
    int win = wid >> 4, head = wid & 15;
    int nw = win & 63;
    int wh = nw >> 3, ww = nw & 7;
    int lane = threadIdx.x;
    __shared__ bf16 Ks[49 * 32];
    __shared__ bf16 Vs[49 * 32];
    const bf16* base = qkv + (size_t)win * 49 * 1536 + head * 32;
    for (int c = lane; c < 196; c += 64) {
        int i = c >> 2, p4 = c & 3;
        *(uint4*)&Ks[i * 32 + p4 * 8] = *(const uint4*)(base + (size_t)i * 1536 + 512 + p4 * 8);
        *(uint4*)&Vs[i * 32 + p4 * 8] = *(const uint4*)(base + (size_t)i * 1536 + 1024 + p4 * 8);
    }
    __syncthreads();
    if (lane >= 49) return;
    float q[32];
    const bf16* qr = base + (size_t)lane * 1536;
#pragma unroll
    for (int d = 0; d < 32; d++) q[d] = (float)qr[d] * 0.17677669529663689f;
    int yi = lane / 7, xi = lane - yi * 7;
    int idi = 3 * regid(wh * 7 + yi) + regid(ww * 7 + xi);
    float p[49];
    float mx = -1e30f;
#pragma unroll
    for (int j = 0; j < 49; j++) {
        float s = 0.f;
#pragma unroll
        for (int d = 0; d < 32; d++) s += q[d] * (float)Ks[j * 32 + d];
        int yj = j / 7, xj = j - yj * 7;
        int idj = 3 * regid(wh * 7 + yj) + regid(ww * 7 + xj);
        int ridx = (yi - yj + 6) * 13 + (xi - xj + 6);
        s += rpb[ridx * 16 + head];
        if (idj != idi) s -= 100.f;
        p[j] = s;
        mx = fmaxf(mx, s);
    }
    float sum = 0.f;
#pragma unroll
    for (int j = 0; j < 49; j++) { p[j] = __expf(p[j] - mx); sum += p[j]; }
    float inv = 1.f / sum;
    float o[32];
#pragma unroll
    for (int d = 0; d < 32; d++) o[d] = 0.f;
#pragma unroll
    for (int j = 0; j < 49; j++) {
        float pv = p[j] * inv;
#pragma unroll
        for (int d = 0; d < 32; d++) o[d] += pv * (float)Vs[j * 32 + d];
    }
    bf16* orow = outp + (size_t)(win * 49 + lane) * 512 + head * 32;
#pragma unroll
    for (int d = 0; d < 32; d++) orow[d] = (bf16)o[d];
}

extern "C" void kernel_launch(void* const* d_in, const int* in_sizes, int n_in,
                              void* d_out, int out_size, void* d_ws, size_t ws_size,
                              hipStream_t stream)
{
    const float* x      = (const float*)d_in[0];
    const float* n1g    = (const float*)d_in[1];
    const float* n1b    = (const float*)d_in[2];
    const float* qkv_w  = (const float*)d_in[3];
    const float* qkv_b  = (const float*)d_in[4];
    const float* proj_w = (const float*)d_in[5];
    const float* proj_b = (const float*)d_in[6];
    const float* rpb    = (const float*)d_in[7];
    const float* n2g    = (const float*)d_in[8];
    const float* n2b    = (const float*)d_in[9];
    const float* fc1_w  = (const float*)d_in[10];
    const float* fc1_b  = (const float*)d_in[11];
    const float* fc2_w  = (const float*)d_in[12];
    const float* fc2_b  = (const float*)d_in[13];

    char* ws = (char*)d_ws;
    // layout (bytes):
    //   [0, 154140672)            qkv bf16 (50176 x 1536)        } hid (50176 x 2048 bf16)
    //   [154140672, 205520896)    h   bf16 (50176 x 512)         }   overlays exactly
    //   [205520896, 256901120)    attn_out bf16 -> later ln2h bf16
    //   [256901120, 263192576)    weights bf16 (qkv_w | proj_w | fc1_w | fc2_w)
    // x1 (fp32, 50176x512) lives in d_out (exact size match).
    bf16* qkv  = (bf16*)ws;
    bf16* h    = (bf16*)(ws + 154140672ull);
    bf16* ao   = (bf16*)(ws + 205520896ull);
    bf16* wbuf = (bf16*)(ws + 256901120ull);
    bf16* hid  = (bf16*)ws;          // overlays qkv+h (dead by then)
    bf16* ln2h = ao;                 // overlays attn_out (dead by then)
    bf16* wq  = wbuf;
    bf16* wp  = wbuf + 786432;
    bf16* wf1 = wbuf + 1048576;
    bf16* wf2 = wbuf + 2097152;
    float* x1 = (float*)d_out;

    convert_w_kernel<<<3072, 256, 0, stream>>>(qkv_w, proj_w, fc1_w, fc2_w, wbuf);
    ln1_window_kernel<<<M_TOK, 256, 0, stream>>>(x, n1g, n1b, h);
    gemm128_kernel<0, 512><<<dim3(12, 392), 256, 0, stream>>>(h, wq, qkv_b, qkv, nullptr, 1536);
    attn_kernel<<<16384, 64, 0, stream>>>(qkv, rpb, ao);
    gemm128_kernel<2, 512><<<dim3(4, 392), 256, 0, stream>>>(ao, wp, proj_b, x1, x, 512);
    ln2_kernel<<<M_TOK, 256, 0, stream>>>(x1, n2g, n2b, ln2h);
    gemm128_kernel<1, 512><<<dim3(16, 392), 256, 0, stream>>>(ln2h, wf1, fc1_b, hid, nullptr, 2048);
    gemm128_kernel<3, 2048><<<dim3(4, 392), 256, 0, stream>>>(hid, wf2, fc2_b, d_out, x1, 512);
}

// Round 4
// 753.152 us; speedup vs baseline: 1.5161x; 1.3128x over previous
//
#include <hip/hip_runtime.h>
#include <hip/hip_bf16.h>

typedef __bf16 bf16;
typedef __bf16 bf16x8 __attribute__((ext_vector_type(8)));
typedef __bf16 bf16x4 __attribute__((ext_vector_type(4)));
typedef __bf16 bf16x2 __attribute__((ext_vector_type(2)));
typedef float f32x4 __attribute__((ext_vector_type(4)));

// B=16, H=W=56, C=512, HEADS=16, hd=32, WS=7, SHIFT=3, N=49, NW=64
#define M_TOK 50176

#define GLD16(dst, src) __builtin_amdgcn_global_load_lds( \
    (const __attribute__((address_space(1))) void*)(src), \
    (__attribute__((address_space(3))) void*)(dst), 16, 0, 0)

// ---------------- weight fp32 -> bf16 conversion (4 segments, packed dst)
__global__ __launch_bounds__(256) void convert_w_kernel(
    const float* __restrict__ w0, const float* __restrict__ w1,
    const float* __restrict__ w2, const float* __restrict__ w3,
    bf16* __restrict__ dst)
{
    int blk = blockIdx.x;
    const float* src; size_t srel, drel;
    if (blk < 768)       { src = w0; srel = (size_t)blk * 1024;          drel = srel; }
    else if (blk < 1024) { src = w1; srel = (size_t)(blk - 768) * 1024;  drel = 786432 + srel; }
    else if (blk < 2048) { src = w2; srel = (size_t)(blk - 1024) * 1024; drel = 1048576 + srel; }
    else                 { src = w3; srel = (size_t)(blk - 2048) * 1024; drel = 2097152 + srel; }
    int i = threadIdx.x * 4;
    float4 v = *(const float4*)(src + srel + i);
    bf16* d = dst + drel + i;
    d[0] = (bf16)v.x; d[1] = (bf16)v.y; d[2] = (bf16)v.z; d[3] = (bf16)v.w;
}

// ---------------- bias+mask table: bt[type][head][q][64]  (k-pad = -1e9)
// type = (wh==7)*2 + (ww==7)
__global__ __launch_bounds__(64) void bias_table_kernel(
    const float* __restrict__ rpb, float* __restrict__ bt)
{
    int tq = blockIdx.x;                  // [0, 4*16*49)
    int type = tq / 784, r = tq - type * 784;
    int head = r / 49, q = r - head * 49;
    int k = threadIdx.x;
    float v;
    if (k < 49) {
        int yq = q / 7, xq = q - yq * 7;
        int yk = k / 7, xk = k - yk * 7;
        int ridx = (yq - yk + 6) * 13 + (xq - xk + 6);
        v = rpb[ridx * 16 + head];
        int th = type >> 1, tw = type & 1;
        int qid = 3 * (th ? (yq < 4 ? 1 : 2) : 0) + (tw ? (xq < 4 ? 1 : 2) : 0);
        int kid = 3 * (th ? (yk < 4 ? 1 : 2) : 0) + (tw ? (xk < 4 ? 1 : 2) : 0);
        if (qid != kid) v -= 100.f;
    } else {
        v = -1e9f;
    }
    bt[(size_t)tq * 64 + k] = v;
}

// ---------------- LN1 + cyclic shift + window partition -> h (window-token order, bf16)
__global__ __launch_bounds__(256) void ln1_window_kernel(
    const float* __restrict__ x, const float* __restrict__ g, const float* __restrict__ bta,
    bf16* __restrict__ h)
{
    int t = blockIdx.x;                 // window-token index
    int win = t / 49, n = t - win * 49;
    int bi = win >> 6, nw = win & 63;
    int wh = nw >> 3, ww = nw & 7;
    int ny = n / 7, nx = n - ny * 7;
    int r = wh * 7 + ny + 3; if (r >= 56) r -= 56;   // roll(-3)
    int c = ww * 7 + nx + 3; if (c >= 56) c -= 56;
    const float* xr = x + ((size_t)bi * 3136 + r * 56 + c) * 512;
    int tid = threadIdx.x;
    float v0 = xr[tid];
    float v1 = xr[tid + 256];
    float s = v0 + v1, ss = v0 * v0 + v1 * v1;
#pragma unroll
    for (int o = 32; o; o >>= 1) { s += __shfl_down(s, o, 64); ss += __shfl_down(ss, o, 64); }
    __shared__ float red[8];
    int wave = tid >> 6, lane = tid & 63;
    if (lane == 0) { red[wave] = s; red[4 + wave] = ss; }
    __syncthreads();
    float S = red[0] + red[1] + red[2] + red[3];
    float SS = red[4] + red[5] + red[6] + red[7];
    float mean = S * (1.f / 512.f);
    float var = SS * (1.f / 512.f) - mean * mean;
    float rstd = rsqrtf(var + 1e-5f);
    bf16* hr = h + (size_t)t * 512;
    hr[tid] = (bf16)((v0 - mean) * rstd * g[tid] + bta[tid]);
    hr[tid + 256] = (bf16)((v1 - mean) * rstd * g[tid + 256] + bta[tid + 256]);
}

// ---------------- LN2 (natural token order), x1 fp32 -> bf16 out
__global__ __launch_bounds__(256) void ln2_kernel(
    const float* __restrict__ x1, const float* __restrict__ g,
    const float* __restrict__ bta, bf16* __restrict__ outp)
{
    int t = blockIdx.x;
    int tid = threadIdx.x;
    const float* xr = x1 + (size_t)t * 512;
    float v0 = xr[tid], v1 = xr[tid + 256];
    float s = v0 + v1, ss = v0 * v0 + v1 * v1;
#pragma unroll
    for (int o = 32; o; o >>= 1) { s += __shfl_down(s, o, 64); ss += __shfl_down(ss, o, 64); }
    __shared__ float red[8];
    int wave = tid >> 6, lane = tid & 63;
    if (lane == 0) { red[wave] = s; red[4 + wave] = ss; }
    __syncthreads();
    float S = red[0] + red[1] + red[2] + red[3];
    float SS = red[4] + red[5] + red[6] + red[7];
    float mean = S * (1.f / 512.f);
    float var = SS * (1.f / 512.f) - mean * mean;
    float rstd = rsqrtf(var + 1e-5f);
    bf16* hr = outp + (size_t)t * 512;
    hr[tid] = (bf16)((v0 - mean) * rstd * g[tid] + bta[tid]);
    hr[tid + 256] = (bf16)((v1 - mean) * rstd * g[tid + 256] + bta[tid + 256]);
}

// ---------------- 128x128 MFMA GEMM (m97 structure)
template <int MODE, int K>
__global__ __launch_bounds__(256) void gemm128_kernel(
    const bf16* __restrict__ A, const bf16* __restrict__ Wt, const float* __restrict__ bias,
    void* __restrict__ outp, const float* __restrict__ extra, int N)
{
    __shared__ bf16 As[128][32];
    __shared__ bf16 Ws[128][32];
    int bn = blockIdx.x, bm = blockIdx.y;
    int tid = threadIdx.x;
    int wave = tid >> 6, lane = tid & 63;
    int wm = wave >> 1, wn = wave & 1;
    int fr = lane & 15, fq = lane >> 4;
    int ko = fq * 8;
    int rs = lane >> 2, cs = (lane & 3) * 8;
    const bf16* gA0 = A + (size_t)(bm * 128 + wave * 32 + rs) * K + cs;
    const bf16* gA1 = gA0 + (size_t)16 * K;
    const bf16* gB0 = Wt + (size_t)(bn * 128 + wave * 32 + rs) * K + cs;
    const bf16* gB1 = gB0 + (size_t)16 * K;
    bf16* lA0 = &As[wave * 32][0];
    bf16* lA1 = &As[wave * 32 + 16][0];
    bf16* lB0 = &Ws[wave * 32][0];
    bf16* lB1 = &Ws[wave * 32 + 16][0];
    f32x4 z = {0.f, 0.f, 0.f, 0.f};
    f32x4 acc[4][4];
#pragma unroll
    for (int mi = 0; mi < 4; mi++)
#pragma unroll
        for (int ni = 0; ni < 4; ni++) acc[mi][ni] = z;

    for (int k0 = 0; k0 < K; k0 += 32) {
        GLD16(lA0, gA0 + k0);
        GLD16(lA1, gA1 + k0);
        GLD16(lB0, gB0 + k0);
        GLD16(lB1, gB1 + k0);
        asm volatile("s_waitcnt vmcnt(0)" ::: "memory");
        __syncthreads();
        bf16x8 a[4], b[4];
#pragma unroll
        for (int i = 0; i < 4; i++) {
            a[i] = *(const bf16x8*)&As[wm * 64 + i * 16 + fr][ko];
            b[i] = *(const bf16x8*)&Ws[wn * 64 + i * 16 + fr][ko];
        }
#pragma unroll
        for (int mi = 0; mi < 4; mi++)
#pragma unroll
            for (int ni = 0; ni < 4; ni++)
                acc[mi][ni] = __builtin_amdgcn_mfma_f32_16x16x32_bf16(a[mi], b[ni], acc[mi][ni], 0, 0, 0);
        __syncthreads();
    }

#pragma unroll
    for (int mi = 0; mi < 4; mi++) {
#pragma unroll
        for (int r = 0; r < 4; r++) {
            int row = bm * 128 + wm * 64 + mi * 16 + fq * 4 + r;
            size_t rowbase;
            if constexpr (MODE == 2) {
                int win = row / 49, n = row - win * 49;
                int bi = win >> 6, nw = win & 63;
                int wh = nw >> 3, wwi = nw & 7;
                int ny = n / 7, nx = n - ny * 7;
                int rr = wh * 7 + ny + 3; if (rr >= 56) rr -= 56;
                int cc = wwi * 7 + nx + 3; if (cc >= 56) cc -= 56;
                rowbase = ((size_t)bi * 3136 + rr * 56 + cc) * 512;
            } else {
                rowbase = (size_t)row * (MODE == 3 ? 512 : N);
            }
#pragma unroll
            for (int ni = 0; ni < 4; ni++) {
                int col = bn * 128 + wn * 64 + ni * 16 + fr;
                float v = acc[mi][ni][r] + bias[col];
                if constexpr (MODE == 0) {
                    ((bf16*)outp)[rowbase + col] = (bf16)v;
                } else if constexpr (MODE == 1) {
                    v = 0.5f * v * (1.f + erff(v * 0.70710678118654752f));
                    ((bf16*)outp)[rowbase + col] = (bf16)v;
                } else {
                    size_t dst = rowbase + col;
                    ((float*)outp)[dst] = v + extra[dst];
                }
            }
        }
    }
}

// ---------------- MFMA attention: one wave per (window, head). N=49 (pad 64), hd=32.
// S^T = mfma(K, Q)  (rows=k, cols=q) -> softmax over rows via regs + shfl_xor(16/32)
// P exchanged via LDS -> O^T = mfma(V^T, P), normalized at store.
__global__ __launch_bounds__(64) void attn_mfma_kernel(
    const bf16* __restrict__ qkv, const float* __restrict__ bt, bf16* __restrict__ outp)
{
    int wid = blockIdx.x;
    int win = wid >> 4, head = wid & 15;
    int nw = win & 63;
    int type = ((nw >> 3) == 7 ? 2 : 0) + ((nw & 7) == 7 ? 1 : 0);
    int lane = threadIdx.x;
    int fr = lane & 15, fq = lane >> 4;
    __shared__ bf16 Vt[32][72];   // V^T, stride 144 B (bank-spread, 16-aligned)
    __shared__ bf16 Ps[64][72];   // P[q][k]
    const bf16* base = qkv + (size_t)win * 49 * 1536;

    // zero Vt (kill stale-LDS NaN risk in k-pad)
    uint4 z4 = {0, 0, 0, 0};
#pragma unroll
    for (int c = lane; c < 288; c += 64) ((uint4*)Vt)[c] = z4;
    __syncthreads();
    // V transpose: Vt[d][tok] = V[tok][d]
    for (int c = lane; c < 1568; c += 64) {
        int tok = c >> 5, d = c & 31;
        Vt[d][tok] = base[(size_t)tok * 1536 + 1024 + head * 32 + d];
    }
    // Q,K fragments direct from global (row-clamped; garbage masked later)
    bf16x8 qf[4], kf[4];
#pragma unroll
    for (int i = 0; i < 4; i++) {
        int tq = i * 16 + fr; if (tq > 48) tq = 48;
        qf[i] = *(const bf16x8*)(base + (size_t)tq * 1536 + head * 32 + fq * 8);
        kf[i] = *(const bf16x8*)(base + (size_t)tq * 1536 + 512 + head * 32 + fq * 8);
    }
    f32x4 z = {0.f, 0.f, 0.f, 0.f};
    f32x4 st[4][4];
#pragma unroll
    for (int mi = 0; mi < 4; mi++)
#pragma unroll
        for (int ni = 0; ni < 4; ni++)
            st[mi][ni] = __builtin_amdgcn_mfma_f32_16x16x32_bf16(kf[mi], qf[ni], z, 0, 0, 0);
    __syncthreads();   // Vt writes complete

    // bias+mask+scale, softmax over k (rows)
    const float* btb = bt + (size_t)(type * 16 + head) * 49 * 64;
    float p[4][4][4];
    float inv[4];
#pragma unroll
    for (int ni = 0; ni < 4; ni++) {
        int q = ni * 16 + fr; if (q > 48) q = 48;
        const float* btr = btb + q * 64;
        float m = -1e30f;
#pragma unroll
        for (int mi = 0; mi < 4; mi++) {
            float4 bv = *(const float4*)(btr + mi * 16 + fq * 4);
#pragma unroll
            for (int r = 0; r < 4; r++) {
                float s = st[mi][ni][r] * 0.17677669529663689f + (&bv.x)[r];
                p[mi][ni][r] = s;
                m = fmaxf(m, s);
            }
        }
        m = fmaxf(m, __shfl_xor(m, 16));
        m = fmaxf(m, __shfl_xor(m, 32));
        float sum = 0.f;
#pragma unroll
        for (int mi = 0; mi < 4; mi++)
#pragma unroll
            for (int r = 0; r < 4; r++) {
                float e = __expf(p[mi][ni][r] - m);
                p[mi][ni][r] = e;
                sum += e;
            }
        sum += __shfl_xor(sum, 16);
        sum += __shfl_xor(sum, 32);
        inv[ni] = 1.f / sum;
    }
    // P -> LDS (bf16), [q][k]
#pragma unroll
    for (int mi = 0; mi < 4; mi++)
#pragma unroll
        for (int ni = 0; ni < 4; ni++) {
            bf16x4 t;
            t[0] = (bf16)p[mi][ni][0]; t[1] = (bf16)p[mi][ni][1];
            t[2] = (bf16)p[mi][ni][2]; t[3] = (bf16)p[mi][ni][3];
            *(bf16x4*)&Ps[ni * 16 + fr][mi * 16 + fq * 4] = t;
        }
    __syncthreads();
    // O^T = mfma(V^T, P): rows=d(32), cols=q(64), kdim=64 (2 steps)
    f32x4 o[2][4];
#pragma unroll
    for (int mi = 0; mi < 2; mi++)
#pragma unroll
        for (int ni = 0; ni < 4; ni++) o[mi][ni] = z;
#pragma unroll
    for (int kt = 0; kt < 2; kt++) {
        bf16x8 a0 = *(const bf16x8*)&Vt[fr][kt * 32 + fq * 8];
        bf16x8 a1 = *(const bf16x8*)&Vt[16 + fr][kt * 32 + fq * 8];
#pragma unroll
        for (int ni = 0; ni < 4; ni++) {
            bf16x8 b = *(const bf16x8*)&Ps[ni * 16 + fr][kt * 32 + fq * 8];
            o[0][ni] = __builtin_amdgcn_mfma_f32_16x16x32_bf16(a0, b, o[0][ni], 0, 0, 0);
            o[1][ni] = __builtin_amdgcn_mfma_f32_16x16x32_bf16(a1, b, o[1][ni], 0, 0, 0);
        }
    }
    // store: out[(win*49+q)*512 + head*32 + d] = o * inv[q]
#pragma unroll
    for (int ni = 0; ni < 4; ni++) {
        int q = ni * 16 + fr;
        if (q < 49) {
            bf16* orow = outp + (size_t)(win * 49 + q) * 512 + head * 32;
#pragma unroll
            for (int mi = 0; mi < 2; mi++)
#pragma unroll
                for (int r2 = 0; r2 < 2; r2++) {
                    bf16x2 t;
                    t[0] = (bf16)(o[mi][ni][2 * r2] * inv[ni]);
                    t[1] = (bf16)(o[mi][ni][2 * r2 + 1] * inv[ni]);
                    *(bf16x2*)(orow + mi * 16 + fq * 4 + 2 * r2) = t;
                }
        }
    }
}

extern "C" void kernel_launch(void* const* d_in, const int* in_sizes, int n_in,
                              void* d_out, int out_size, void* d_ws, size_t ws_size,
                              hipStream_t stream)
{
    const float* x      = (const float*)d_in[0];
    const float* n1g    = (const float*)d_in[1];
    const float* n1b    = (const float*)d_in[2];
    const float* qkv_w  = (const float*)d_in[3];
    const float* qkv_b  = (const float*)d_in[4];
    const float* proj_w = (const float*)d_in[5];
    const float* proj_b = (const float*)d_in[6];
    const float* rpb    = (const float*)d_in[7];
    const float* n2g    = (const float*)d_in[8];
    const float* n2b    = (const float*)d_in[9];
    const float* fc1_w  = (const float*)d_in[10];
    const float* fc1_b  = (const float*)d_in[11];
    const float* fc2_w  = (const float*)d_in[12];
    const float* fc2_b  = (const float*)d_in[13];

    char* ws = (char*)d_ws;
    // layout (bytes):
    //   [0, 154140672)            qkv bf16 (50176 x 1536)        } hid (50176 x 2048 bf16)
    //   [154140672, 205520896)    h bf16 (dead after qkv GEMM -> bt fp32 803KB lives here)
    //   [205520896, 256901120)    attn_out bf16 -> later ln2h bf16
    //   [256901120, 263192576)    weights bf16 (qkv_w | proj_w | fc1_w | fc2_w)
    // x1 (fp32, 50176x512) lives in d_out.
    bf16* qkv  = (bf16*)ws;
    bf16* h    = (bf16*)(ws + 154140672ull);
    float* bt  = (float*)(ws + 154140672ull);   // overlays h after qkv GEMM
    bf16* ao   = (bf16*)(ws + 205520896ull);
    bf16* wbuf = (bf16*)(ws + 256901120ull);
    bf16* hid  = (bf16*)ws;
    bf16* ln2h = ao;
    bf16* wq  = wbuf;
    bf16* wp  = wbuf + 786432;
    bf16* wf1 = wbuf + 1048576;
    bf16* wf2 = wbuf + 2097152;
    float* x1 = (float*)d_out;

    convert_w_kernel<<<3072, 256, 0, stream>>>(qkv_w, proj_w, fc1_w, fc2_w, wbuf);
    ln1_window_kernel<<<M_TOK, 256, 0, stream>>>(x, n1g, n1b, h);
    gemm128_kernel<0, 512><<<dim3(12, 392), 256, 0, stream>>>(h, wq, qkv_b, qkv, nullptr, 1536);
    bias_table_kernel<<<3136, 64, 0, stream>>>(rpb, bt);   // after qkv GEMM (overlays h)
    attn_mfma_kernel<<<16384, 64, 0, stream>>>(qkv, bt, ao);
    gemm128_kernel<2, 512><<<dim3(4, 392), 256, 0, stream>>>(ao, wp, proj_b, x1, x, 512);
    ln2_kernel<<<M_TOK, 256, 0, stream>>>(x1, n2g, n2b, ln2h);
    gemm128_kernel<1, 512><<<dim3(16, 392), 256, 0, stream>>>(ln2h, wf1, fc1_b, hid, nullptr, 2048);
    gemm128_kernel<3, 2048><<<dim3(4, 392), 256, 0, stream>>>(hid, wf2, fc2_b, d_out, x1, 512);
}